// Round 18
// baseline (631.808 us; speedup 1.0000x reference)
//
#include <hip/hip_runtime.h>
#include <hip/hip_fp16.h>

#define NN 100000
#define EE 1000000
#define ELL 500000
#define NF (NN*64)
#define NB_SCAN ((NN + 1023) / 1024)   // 98

// ws layouts (floats)
#define OFF_CNT    100352
#define OFF_BSUM   200704
#define OFF_RPA    200832
#define OFF_COLA   301184
#define OFF_RPB    1301184
#define OFF_COLB   1401536
#define WS_SINGLE  (1301184 + 3*NF)              // 82.0 MB
#define WS_DUAL    (2401536 + 5*NF)              // 137.6 MB

// ---------------- Threefry-2x32 ----------------
__device__ __forceinline__ void threefry2x32(unsigned k0, unsigned k1, unsigned &x0, unsigned &x1){
  unsigned ks2 = k0 ^ k1 ^ 0x1BD11BDAu;
#define TF_R(R) { x0 += x1; x1 = (x1<<(R))|(x1>>(32-(R))); x1 ^= x0; }
  x0 += k0; x1 += k1;
  TF_R(13) TF_R(15) TF_R(26) TF_R(6)
  x0 += k1;  x1 += ks2 + 1u;
  TF_R(17) TF_R(29) TF_R(16) TF_R(24)
  x0 += ks2; x1 += k0 + 2u;
  TF_R(13) TF_R(15) TF_R(26) TF_R(6)
  x0 += k0;  x1 += k1 + 3u;
  TF_R(17) TF_R(29) TF_R(16) TF_R(24)
  x0 += k1;  x1 += ks2 + 4u;
  TF_R(13) TF_R(15) TF_R(26) TF_R(6)
  x0 += ks2; x1 += k0 + 5u;
#undef TF_R
}

__device__ __forceinline__ float dropout_val(float v, unsigned i){
  unsigned x0 = 0u, x1 = i;
  threefry2x32(0u, 42u, x0, x1);
  unsigned bits = x0 ^ x1;
  float u = __uint_as_float((bits >> 9) | 0x3f800000u) - 1.0f;
  return (u < 0.6f) ? v * (1.0f/0.6f) : 0.0f;
}

__global__ void k_probe(const int* __restrict__ ei, unsigned hostbits, float* __restrict__ out){
  if (threadIdx.x != 0 || blockIdx.x != 0) return;
  unsigned bits = hostbits;
  { unsigned a=0u, b=0u; threefry2x32(0u, 0u, a, b);
    if (a != 0x6b200159u || b != 0x99ba4efeu) bits |= 1u; }
  if (bits) out[0] = 1.0e4f * (float)bits;
}

// ---------------- fp16 pack/unpack ----------------
__device__ __forceinline__ uint2 f4_to_h4(float4 v){
  __half2 lo = __floats2half2_rn(v.x, v.y);
  __half2 hi = __floats2half2_rn(v.z, v.w);
  uint2 r; r.x = *(unsigned*)&lo; r.y = *(unsigned*)&hi; return r;
}
__device__ __forceinline__ float4 h4_to_f4(uint2 u){
  __half2 lo = *(__half2*)&u.x;
  __half2 hi = *(__half2*)&u.y;
  float2 a = __half22float2(lo), b = __half22float2(hi);
  return make_float4(a.x, a.y, b.x, b.y);
}

// ---------------- utility ----------------
__global__ void k_zero_int(int* __restrict__ p, int n){
  int i = blockIdx.x*256 + threadIdx.x;
  if (i < n) p[i] = 0;
}

__global__ void k_zerof(int* __restrict__ cnt, int n, int* __restrict__ flag){
  int i = blockIdx.x*256 + threadIdx.x;
  if (i < n) cnt[i] = 0;
  if (i == 0) *flag = 0;
}

__global__ void k_deg(const int* __restrict__ dst, int ne, int* __restrict__ cnt){
  int i = blockIdx.x*256 + threadIdx.x;
  if (i < ne) atomicAdd(&cnt[dst[i]], 1);
}

__global__ void k_degrank(const int* __restrict__ dst, int ne, int* __restrict__ cnt,
                          int* __restrict__ rank){
  int i = blockIdx.x*256 + threadIdx.x;
  if (i >= ne) return;
  rank[i] = atomicAdd(&cnt[dst[i]], 1);
}

__global__ void k_dinv(const int* __restrict__ cnt, float* __restrict__ dinv, int n){
  int i = blockIdx.x*256 + threadIdx.x;
  if (i < n) dinv[i] = 1.0f / sqrtf((float)(cnt[i] + 1));
}

// ---------------- fused single-launch scan (98 blocks, device spin barrier) + dinv ----------------
__global__ __launch_bounds__(1024) void k_scanfused(const int* __restrict__ cnt, int* __restrict__ bsum,
                                                    int* __restrict__ flag, int* __restrict__ rowptr,
                                                    float* __restrict__ dinv, int computeDinv, int n){
  __shared__ int lds[1024];
  __shared__ int ps[128];
  int t = threadIdx.x;
  int i = blockIdx.x*1024 + t;
  int v = (i < n) ? cnt[i] : 0;
  if (computeDinv && i < n) dinv[i] = 1.0f / sqrtf((float)(v + 1));
  lds[t] = v;
  __syncthreads();
  for (int off = 1; off < 1024; off <<= 1){
    int x = (t >= off) ? lds[t - off] : 0;
    __syncthreads();
    lds[t] += x;
    __syncthreads();
  }
  int incl = lds[t];
  if (t == 1023){
    bsum[blockIdx.x] = lds[1023];
    __threadfence();
    atomicAdd(flag, 1);
  }
  if (t == 0){
    while (atomicAdd(flag, 0) < NB_SCAN) { }
  }
  __syncthreads();
  if (t < 128) ps[t] = (t < blockIdx.x) ? bsum[t] : 0;
  __syncthreads();
  if (t < 64) ps[t] += ps[t + 64];
  __syncthreads();
  if (t < 32) ps[t] += ps[t + 32];
  __syncthreads();
  if (t < 16) ps[t] += ps[t + 16];
  __syncthreads();
  if (t < 8)  ps[t] += ps[t + 8];
  __syncthreads();
  if (t < 4)  ps[t] += ps[t + 4];
  __syncthreads();
  if (t < 2)  ps[t] += ps[t + 2];
  __syncthreads();
  if (t < 1)  ps[t] += ps[t + 1];
  __syncthreads();
  int excl = incl - v + ps[0];
  if (i < n)  rowptr[i] = excl;
  if (i == n-1) rowptr[n] = excl + v;
}

// ---------------- CSR fill, atomic-free; also re-zeroes cnt+flag for the NEXT build ----------------
__global__ void k_fillrz(const int* __restrict__ src, const int* __restrict__ dst, int ne,
                         const int* __restrict__ rowptr, const int* __restrict__ rank,
                         int* __restrict__ col, int* __restrict__ cnt, int* __restrict__ flag){
  int e = blockIdx.x*256 + threadIdx.x;
  if (e < NN) cnt[e] = 0;
  if (e == 0) *flag = 0;
  if (e >= ne) return;
  col[rowptr[dst[e]] + rank[e]] = src[e];
}

__global__ void k_fillr(const int* __restrict__ src, const int* __restrict__ dst, int ne,
                        const int* __restrict__ rowptr, const int* __restrict__ rank,
                        int* __restrict__ col){
  int e = blockIdx.x*256 + threadIdx.x;
  if (e >= ne) return;
  col[rowptr[dst[e]] + rank[e]] = src[e];
}

// ---------------- GEMM [nrows,64] @ [64,64]; f32 out ----------------
template<bool RELU, bool SCALE>
__global__ __launch_bounds__(256) void k_gemm64(const float* __restrict__ X, const float* __restrict__ W,
                                                const float* __restrict__ dinv,
                                                int nrows, float* __restrict__ Y){
  __shared__ float Ws[64][64];
  int t = threadIdx.x;
  {
    const float4* W4 = (const float4*)W;
    float4* S4 = (float4*)&Ws[0][0];
    #pragma unroll
    for (int i = 0; i < 4; ++i) S4[t + 256*i] = W4[t + 256*i];
  }
  __syncthreads();
  int row = blockIdx.x*16 + (t>>4);
  if (row >= nrows) return;
  int c0 = (t & 15) * 4;
  const float4* Xr = (const float4*)(X + (size_t)row*64);
  float4 acc = make_float4(0.f,0.f,0.f,0.f);
  #pragma unroll
  for (int kk = 0; kk < 16; ++kk){
    float4 xv = Xr[kk];
    if (RELU){
      xv.x = fmaxf(xv.x, 0.f); xv.y = fmaxf(xv.y, 0.f);
      xv.z = fmaxf(xv.z, 0.f); xv.w = fmaxf(xv.w, 0.f);
    }
    int k = kk*4;
    float4 w0 = *(const float4*)&Ws[k+0][c0];
    float4 w1 = *(const float4*)&Ws[k+1][c0];
    float4 w2 = *(const float4*)&Ws[k+2][c0];
    float4 w3 = *(const float4*)&Ws[k+3][c0];
    acc.x = fmaf(xv.x, w0.x, acc.x); acc.y = fmaf(xv.x, w0.y, acc.y);
    acc.z = fmaf(xv.x, w0.z, acc.z); acc.w = fmaf(xv.x, w0.w, acc.w);
    acc.x = fmaf(xv.y, w1.x, acc.x); acc.y = fmaf(xv.y, w1.y, acc.y);
    acc.z = fmaf(xv.y, w1.z, acc.z); acc.w = fmaf(xv.y, w1.w, acc.w);
    acc.x = fmaf(xv.z, w2.x, acc.x); acc.y = fmaf(xv.z, w2.y, acc.y);
    acc.z = fmaf(xv.z, w2.z, acc.z); acc.w = fmaf(xv.z, w2.w, acc.w);
    acc.x = fmaf(xv.w, w3.x, acc.x); acc.y = fmaf(xv.w, w3.y, acc.y);
    acc.z = fmaf(xv.w, w3.z, acc.z); acc.w = fmaf(xv.w, w3.w, acc.w);
  }
  if (SCALE){
    float dv = dinv[row];
    acc.x *= dv; acc.y *= dv; acc.z *= dv; acc.w *= dv;
  }
  *(float4*)(Y + (size_t)row*64 + c0) = acc;
}

// ---------------- GEMM f32-in -> fp16 table out ----------------
template<bool RELU>
__global__ __launch_bounds__(256) void k_gemm64h(const float* __restrict__ X, const float* __restrict__ W,
                                                 const float* __restrict__ dinv,
                                                 int nrows, uint2* __restrict__ Y16){
  __shared__ float Ws[64][64];
  int t = threadIdx.x;
  {
    const float4* W4 = (const float4*)W;
    float4* S4 = (float4*)&Ws[0][0];
    #pragma unroll
    for (int i = 0; i < 4; ++i) S4[t + 256*i] = W4[t + 256*i];
  }
  __syncthreads();
  int row = blockIdx.x*16 + (t>>4);
  if (row >= nrows) return;
  int c0 = (t & 15) * 4;
  const float4* Xr = (const float4*)(X + (size_t)row*64);
  float4 acc = make_float4(0.f,0.f,0.f,0.f);
  #pragma unroll
  for (int kk = 0; kk < 16; ++kk){
    float4 xv = Xr[kk];
    if (RELU){
      xv.x = fmaxf(xv.x, 0.f); xv.y = fmaxf(xv.y, 0.f);
      xv.z = fmaxf(xv.z, 0.f); xv.w = fmaxf(xv.w, 0.f);
    }
    int k = kk*4;
    float4 w0 = *(const float4*)&Ws[k+0][c0];
    float4 w1 = *(const float4*)&Ws[k+1][c0];
    float4 w2 = *(const float4*)&Ws[k+2][c0];
    float4 w3 = *(const float4*)&Ws[k+3][c0];
    acc.x = fmaf(xv.x, w0.x, acc.x); acc.y = fmaf(xv.x, w0.y, acc.y);
    acc.z = fmaf(xv.x, w0.z, acc.z); acc.w = fmaf(xv.x, w0.w, acc.w);
    acc.x = fmaf(xv.y, w1.x, acc.x); acc.y = fmaf(xv.y, w1.y, acc.y);
    acc.z = fmaf(xv.y, w1.z, acc.z); acc.w = fmaf(xv.y, w1.w, acc.w);
    acc.x = fmaf(xv.z, w2.x, acc.x); acc.y = fmaf(xv.z, w2.y, acc.y);
    acc.z = fmaf(xv.z, w2.z, acc.z); acc.w = fmaf(xv.z, w2.w, acc.w);
    acc.x = fmaf(xv.w, w3.x, acc.x); acc.y = fmaf(xv.w, w3.y, acc.y);
    acc.z = fmaf(xv.w, w3.z, acc.z); acc.w = fmaf(xv.w, w3.w, acc.w);
  }
  float dv = dinv[row];
  acc.x *= dv; acc.y *= dv; acc.z *= dv; acc.w *= dv;
  Y16[(size_t)row*16 + (t & 15)] = f4_to_h4(acc);
}

// ---------------- GEMM [nrows,64] @ [64,2] ----------------
template<bool RELU, bool SCALE>
__global__ __launch_bounds__(256) void k_gemm2(const float* __restrict__ X, const float* __restrict__ W,
                                               const float* __restrict__ dinv,
                                               int nrows, float* __restrict__ Y){
  __shared__ float Ws[128];
  int t = threadIdx.x;
  if (t < 128) Ws[t] = W[t];
  __syncthreads();
  int row = blockIdx.x*256 + t;
  if (row >= nrows) return;
  const float4* Xr = (const float4*)(X + (size_t)row*64);
  float a0 = 0.f, a1 = 0.f;
  #pragma unroll
  for (int kk = 0; kk < 16; ++kk){
    float4 xv = Xr[kk];
    if (RELU){ xv.x=fmaxf(xv.x,0.f); xv.y=fmaxf(xv.y,0.f); xv.z=fmaxf(xv.z,0.f); xv.w=fmaxf(xv.w,0.f); }
    int k = kk*4;
    a0 = fmaf(xv.x, Ws[2*k+0], a0); a1 = fmaf(xv.x, Ws[2*k+1], a1);
    a0 = fmaf(xv.y, Ws[2*k+2], a0); a1 = fmaf(xv.y, Ws[2*k+3], a1);
    a0 = fmaf(xv.z, Ws[2*k+4], a0); a1 = fmaf(xv.z, Ws[2*k+5], a1);
    a0 = fmaf(xv.w, Ws[2*k+6], a0); a1 = fmaf(xv.w, Ws[2*k+7], a1);
  }
  if (SCALE){ float dv = dinv[row]; a0 *= dv; a1 *= dv; }
  Y[(size_t)row*2]   = a0;
  Y[(size_t)row*2+1] = a1;
}

// ---------------- pipelined row-gather helpers ----------------
__device__ __forceinline__ float4 gather_rows4(const int* __restrict__ col, int beg, int end,
                                               const float4* __restrict__ h4, int fq, float4 acc){
  int j = beg;
  bool p0 = j   < end; int c0 = p0 ? col[j]   : 0;
  bool p1 = j+1 < end; int c1 = p1 ? col[j+1] : 0;
  bool p2 = j+2 < end; int c2 = p2 ? col[j+2] : 0;
  bool p3 = j+3 < end; int c3 = p3 ? col[j+3] : 0;
  while (p0){
    float4 v0 = h4[(size_t)c0*16 + fq];
    float4 v1 = p1 ? h4[(size_t)c1*16 + fq] : make_float4(0.f,0.f,0.f,0.f);
    float4 v2 = p2 ? h4[(size_t)c2*16 + fq] : make_float4(0.f,0.f,0.f,0.f);
    float4 v3 = p3 ? h4[(size_t)c3*16 + fq] : make_float4(0.f,0.f,0.f,0.f);
    j += 4;
    bool q0 = j < end, q1 = j+1 < end, q2 = j+2 < end, q3 = j+3 < end;
    int n0 = q0 ? col[j]   : 0;
    int n1 = q1 ? col[j+1] : 0;
    int n2 = q2 ? col[j+2] : 0;
    int n3 = q3 ? col[j+3] : 0;
    acc.x += v0.x + v1.x + v2.x + v3.x;
    acc.y += v0.y + v1.y + v2.y + v3.y;
    acc.z += v0.z + v1.z + v2.z + v3.z;
    acc.w += v0.w + v1.w + v2.w + v3.w;
    p0=q0; p1=q1; p2=q2; p3=q3; c0=n0; c1=n1; c2=n2; c3=n3;
  }
  return acc;
}

// 8-deep pipelined fp16 gather: 8 row-loads in flight per thread
__device__ __forceinline__ float4 gather_rows8_h16(const int* __restrict__ col, int beg, int end,
                                                   const uint2* __restrict__ h16, int fq, float4 acc){
  const uint2 z = make_uint2(0u, 0u);
  int j = beg;
  bool p0 = j   < end; int c0 = p0 ? col[j]   : 0;
  bool p1 = j+1 < end; int c1 = p1 ? col[j+1] : 0;
  bool p2 = j+2 < end; int c2 = p2 ? col[j+2] : 0;
  bool p3 = j+3 < end; int c3 = p3 ? col[j+3] : 0;
  bool p4 = j+4 < end; int c4 = p4 ? col[j+4] : 0;
  bool p5 = j+5 < end; int c5 = p5 ? col[j+5] : 0;
  bool p6 = j+6 < end; int c6 = p6 ? col[j+6] : 0;
  bool p7 = j+7 < end; int c7 = p7 ? col[j+7] : 0;
  while (p0){
    uint2 u0 = h16[(size_t)c0*16 + fq];
    uint2 u1 = p1 ? h16[(size_t)c1*16 + fq] : z;
    uint2 u2 = p2 ? h16[(size_t)c2*16 + fq] : z;
    uint2 u3 = p3 ? h16[(size_t)c3*16 + fq] : z;
    uint2 u4 = p4 ? h16[(size_t)c4*16 + fq] : z;
    uint2 u5 = p5 ? h16[(size_t)c5*16 + fq] : z;
    uint2 u6 = p6 ? h16[(size_t)c6*16 + fq] : z;
    uint2 u7 = p7 ? h16[(size_t)c7*16 + fq] : z;
    j += 8;
    bool q0 = j   < end, q1 = j+1 < end, q2 = j+2 < end, q3 = j+3 < end;
    bool q4 = j+4 < end, q5 = j+5 < end, q6 = j+6 < end, q7 = j+7 < end;
    int n0 = q0 ? col[j]   : 0;
    int n1 = q1 ? col[j+1] : 0;
    int n2 = q2 ? col[j+2] : 0;
    int n3 = q3 ? col[j+3] : 0;
    int n4 = q4 ? col[j+4] : 0;
    int n5 = q5 ? col[j+5] : 0;
    int n6 = q6 ? col[j+6] : 0;
    int n7 = q7 ? col[j+7] : 0;
    float4 v0 = h4_to_f4(u0), v1 = h4_to_f4(u1), v2 = h4_to_f4(u2), v3 = h4_to_f4(u3);
    float4 v4 = h4_to_f4(u4), v5 = h4_to_f4(u5), v6 = h4_to_f4(u6), v7 = h4_to_f4(u7);
    acc.x += (v0.x + v1.x + v2.x + v3.x) + (v4.x + v5.x + v6.x + v7.x);
    acc.y += (v0.y + v1.y + v2.y + v3.y) + (v4.y + v5.y + v6.y + v7.y);
    acc.z += (v0.z + v1.z + v2.z + v3.z) + (v4.z + v5.z + v6.z + v7.z);
    acc.w += (v0.w + v1.w + v2.w + v3.w) + (v4.w + v5.w + v6.w + v7.w);
    p0=q0; p1=q1; p2=q2; p3=q3; p4=q4; p5=q5; p6=q6; p7=q7;
    c0=n0; c1=n1; c2=n2; c3=n3; c4=n4; c5=n5; c6=n6; c7=n7;
  }
  return acc;
}

// ---------------- CSR gather conv, f32 (single tier) ----------------
__global__ __launch_bounds__(256) void k_gather64(const int* __restrict__ rowptr, const int* __restrict__ col,
                                                  const float* __restrict__ h, const float* __restrict__ dinv,
                                                  const float* __restrict__ b, float* __restrict__ out){
  int gt = blockIdx.x*256 + threadIdx.x;
  int fq = gt & 15;
  int node = gt >> 4;
  if (node >= NN) return;
  const float4* __restrict__ h4 = (const float4*)h;
  float4 acc = h4[(size_t)node*16 + fq];
  acc = gather_rows4(col, rowptr[node], rowptr[node+1], h4, fq, acc);
  float dv = dinv[node];
  float4 bb = ((const float4*)b)[fq];
  float4 r;
  r.x = fmaf(acc.x, dv, bb.x); r.y = fmaf(acc.y, dv, bb.y);
  r.z = fmaf(acc.z, dv, bb.z); r.w = fmaf(acc.w, dv, bb.w);
  *(float4*)(out + (size_t)node*64 + fq*4) = r;
}

// ---------------- CSR gather conv, fp16 in -> fp16 out ----------------
__global__ __launch_bounds__(256) void k_gather64hh(const int* __restrict__ rowptr, const int* __restrict__ col,
                                                    const uint2* __restrict__ h16, const float* __restrict__ dinv,
                                                    const float* __restrict__ b, uint2* __restrict__ out16){
  int gt = blockIdx.x*256 + threadIdx.x;
  int fq = gt & 15;
  int node = gt >> 4;
  if (node >= NN) return;
  float4 acc = h4_to_f4(h16[(size_t)node*16 + fq]);
  acc = gather_rows8_h16(col, rowptr[node], rowptr[node+1], h16, fq, acc);
  float dv = dinv[node];
  float4 bb = ((const float4*)b)[fq];
  float4 r;
  r.x = fmaf(acc.x, dv, bb.x); r.y = fmaf(acc.y, dv, bb.y);
  r.z = fmaf(acc.z, dv, bb.z); r.w = fmaf(acc.w, dv, bb.w);
  out16[(size_t)node*16 + fq] = f4_to_h4(r);
}

// ---------------- FUSED: gather conv1(fp16) + ReLU + @W2 + scale -> fp16 table ----------------
__global__ __launch_bounds__(256) void k_gathergemmh(const int* __restrict__ rowptr, const int* __restrict__ col,
                                                     const uint2* __restrict__ h16, const float* __restrict__ dinv,
                                                     const float* __restrict__ b1, const float* __restrict__ W2,
                                                     uint2* __restrict__ Y16){
  __shared__ float Ws[64][64];
  __shared__ float rows[16][68];
  int t = threadIdx.x;
  {
    const float4* W4 = (const float4*)W2;
    float4* S4 = (float4*)&Ws[0][0];
    #pragma unroll
    for (int i = 0; i < 4; ++i) S4[t + 256*i] = W4[t + 256*i];
  }
  __syncthreads();
  int fq = t & 15, grp = t >> 4;
  int node = blockIdx.x*16 + grp;
  bool alive = node < NN;
  float dv = 0.f;
  if (alive){
    float4 acc = h4_to_f4(h16[(size_t)node*16 + fq]);
    acc = gather_rows8_h16(col, rowptr[node], rowptr[node+1], h16, fq, acc);
    dv = dinv[node];
    float4 bb = ((const float4*)b1)[fq];
    float4 r;
    r.x = fmaxf(fmaf(acc.x, dv, bb.x), 0.f);
    r.y = fmaxf(fmaf(acc.y, dv, bb.y), 0.f);
    r.z = fmaxf(fmaf(acc.z, dv, bb.z), 0.f);
    r.w = fmaxf(fmaf(acc.w, dv, bb.w), 0.f);
    *(float4*)&rows[grp][fq*4] = r;
  }
  __syncthreads();
  if (alive){
    const float* __restrict__ row = &rows[grp][0];
    float4 o = make_float4(0.f,0.f,0.f,0.f);
    int c0 = fq*4;
    #pragma unroll 8
    for (int k = 0; k < 64; ++k){
      float rv = row[k];
      float4 w = *(const float4*)&Ws[k][c0];
      o.x = fmaf(rv, w.x, o.x); o.y = fmaf(rv, w.y, o.y);
      o.z = fmaf(rv, w.z, o.z); o.w = fmaf(rv, w.w, o.w);
    }
    o.x *= dv; o.y *= dv; o.z *= dv; o.w *= dv;
    Y16[(size_t)node*16 + fq] = f4_to_h4(o);
  }
}

// f32 version (single tier)
__global__ __launch_bounds__(256) void k_gathergemm(const int* __restrict__ rowptr, const int* __restrict__ col,
                                                    const float* __restrict__ h, const float* __restrict__ dinv,
                                                    const float* __restrict__ b1, const float* __restrict__ W2,
                                                    float* __restrict__ Y){
  __shared__ float Ws[64][64];
  __shared__ float rows[16][68];
  int t = threadIdx.x;
  {
    const float4* W4 = (const float4*)W2;
    float4* S4 = (float4*)&Ws[0][0];
    #pragma unroll
    for (int i = 0; i < 4; ++i) S4[t + 256*i] = W4[t + 256*i];
  }
  __syncthreads();
  int fq = t & 15, grp = t >> 4;
  int node = blockIdx.x*16 + grp;
  bool alive = node < NN;
  float dv = 0.f;
  if (alive){
    const float4* __restrict__ h4 = (const float4*)h;
    float4 acc = h4[(size_t)node*16 + fq];
    acc = gather_rows4(col, rowptr[node], rowptr[node+1], h4, fq, acc);
    dv = dinv[node];
    float4 bb = ((const float4*)b1)[fq];
    float4 r;
    r.x = fmaxf(fmaf(acc.x, dv, bb.x), 0.f);
    r.y = fmaxf(fmaf(acc.y, dv, bb.y), 0.f);
    r.z = fmaxf(fmaf(acc.z, dv, bb.z), 0.f);
    r.w = fmaxf(fmaf(acc.w, dv, bb.w), 0.f);
    *(float4*)&rows[grp][fq*4] = r;
  }
  __syncthreads();
  if (alive){
    const float* __restrict__ row = &rows[grp][0];
    float4 o = make_float4(0.f,0.f,0.f,0.f);
    int c0 = fq*4;
    #pragma unroll 8
    for (int k = 0; k < 64; ++k){
      float rv = row[k];
      float4 w = *(const float4*)&Ws[k][c0];
      o.x = fmaf(rv, w.x, o.x); o.y = fmaf(rv, w.y, o.y);
      o.z = fmaf(rv, w.z, o.z); o.w = fmaf(rv, w.w, o.w);
    }
    o.x *= dv; o.y *= dv; o.z *= dv; o.w *= dv;
    *(float4*)(Y + (size_t)node*64 + fq*4) = o;
  }
}

// ---------------- FUSED: lf-gather (fp16, CSR-A) + cross-layer agg (fp16 last, CSR-B) + scale (+drop) ----------------
template<bool DROP, bool OUT16>
__global__ __launch_bounds__(256) void k_gatherlfagg2h(const int* __restrict__ rpA, const int* __restrict__ colA,
                                                       const uint2* __restrict__ h16, const float* __restrict__ dinv,
                                                       const float* __restrict__ b,
                                                       const int* __restrict__ rpB, const int* __restrict__ colB,
                                                       const uint2* __restrict__ last16,
                                                       const float* __restrict__ ds, int dsidx,
                                                       void* __restrict__ outv){
  int gt = blockIdx.x*256 + threadIdx.x;
  int fq = gt & 15;
  int node = gt >> 4;
  if (node >= NN) return;
  float4 acc = h4_to_f4(h16[(size_t)node*16 + fq]);
  acc = gather_rows8_h16(colA, rpA[node], rpA[node+1], h16, fq, acc);
  float dv = dinv[node];
  float4 bb = ((const float4*)b)[fq];
  float4 lf;
  lf.x = fmaf(acc.x, dv, bb.x); lf.y = fmaf(acc.y, dv, bb.y);
  lf.z = fmaf(acc.z, dv, bb.z); lf.w = fmaf(acc.w, dv, bb.w);
  float4 agg = gather_rows8_h16(colB, rpB[node], rpB[node+1], last16, fq,
                                make_float4(0.f,0.f,0.f,0.f));
  float inv = 1.0f / ds[dsidx];
  float4 r;
  r.x = (lf.x + agg.x) * inv; r.y = (lf.y + agg.y) * inv;
  r.z = (lf.z + agg.z) * inv; r.w = (lf.w + agg.w) * inv;
  if (DROP){
    unsigned base_i = (unsigned)node*64u + (unsigned)fq*4u;
    r.x = dropout_val(r.x, base_i + 0);
    r.y = dropout_val(r.y, base_i + 1);
    r.z = dropout_val(r.z, base_i + 2);
    r.w = dropout_val(r.w, base_i + 3);
  }
  if (OUT16) ((uint2*)outv)[(size_t)node*16 + fq] = f4_to_h4(r);
  else       *(float4*)((float*)outv + (size_t)node*64 + fq*4) = r;
}

// ---------------- CSR gather cross-layer agg f32 (single tier) ----------------
template<bool DROP>
__global__ __launch_bounds__(256) void k_agggather(const int* __restrict__ rowptr, const int* __restrict__ col,
                                                    const float* __restrict__ lf, const float* __restrict__ last,
                                                    const float* __restrict__ ds, int dsidx, float* __restrict__ out){
  int gt = blockIdx.x*256 + threadIdx.x;
  int fq = gt & 15;
  int node = gt >> 4;
  if (node >= NN) return;
  float4 acc = ((const float4*)lf)[(size_t)node*16 + fq];
  acc = gather_rows4(col, rowptr[node], rowptr[node+1], (const float4*)last, fq, acc);
  float inv = 1.0f / ds[dsidx];
  float4 r;
  r.x = acc.x * inv; r.y = acc.y * inv; r.z = acc.z * inv; r.w = acc.w * inv;
  if (DROP){
    unsigned base_i = (unsigned)node*64u + (unsigned)fq*4u;
    r.x = dropout_val(r.x, base_i + 0);
    r.y = dropout_val(r.y, base_i + 1);
    r.z = dropout_val(r.z, base_i + 2);
    r.w = dropout_val(r.w, base_i + 3);
  }
  *(float4*)(out + (size_t)node*64 + fq*4) = r;
}

// ---------------- FUSED predictor tail: gather(H0) + pb1 + relu + @pW2 + dv -> [N,2] ----------------
__global__ __launch_bounds__(256) void k_predgather2h(const int* __restrict__ rowptr, const int* __restrict__ col,
                                                      const uint2* __restrict__ h16, const float* __restrict__ dinv,
                                                      const float* __restrict__ b1, const float* __restrict__ W2,
                                                      float* __restrict__ Y){
  int gt = blockIdx.x*256 + threadIdx.x;
  int fq = gt & 15;
  int node = gt >> 4;
  if (node >= NN) return;
  float4 acc = h4_to_f4(h16[(size_t)node*16 + fq]);
  acc = gather_rows8_h16(col, rowptr[node], rowptr[node+1], h16, fq, acc);
  float dv = dinv[node];
  float4 bb = ((const float4*)b1)[fq];
  float4 r;
  r.x = fmaxf(fmaf(acc.x, dv, bb.x), 0.f);
  r.y = fmaxf(fmaf(acc.y, dv, bb.y), 0.f);
  r.z = fmaxf(fmaf(acc.z, dv, bb.z), 0.f);
  r.w = fmaxf(fmaf(acc.w, dv, bb.w), 0.f);
  const float4* w4 = (const float4*)W2;
  float4 wa = w4[fq*2], wb = w4[fq*2 + 1];
  float o0 = r.x*wa.x + r.y*wa.z + r.z*wb.x + r.w*wb.z;
  float o1 = r.x*wa.y + r.y*wa.w + r.z*wb.y + r.w*wb.w;
  o0 += __shfl_xor(o0, 1); o1 += __shfl_xor(o1, 1);
  o0 += __shfl_xor(o0, 2); o1 += __shfl_xor(o1, 2);
  o0 += __shfl_xor(o0, 4); o1 += __shfl_xor(o1, 4);
  o0 += __shfl_xor(o0, 8); o1 += __shfl_xor(o1, 8);
  if (fq == 0){
    Y[(size_t)node*2]   = o0 * dv;
    Y[(size_t)node*2+1] = o1 * dv;
  }
}

// ---------------- CSR gather final conv (D_out=2) ----------------
__global__ void k_gather2(const int* __restrict__ rowptr, const int* __restrict__ col,
                          const float* __restrict__ h2, const float* __restrict__ dinv,
                          const float* __restrict__ b, float* __restrict__ out){
  int d = blockIdx.x*256 + threadIdx.x;
  if (d >= NN) return;
  int beg = rowptr[d], end = rowptr[d+1];
  float a0 = h2[(size_t)d*2];
  float a1 = h2[(size_t)d*2+1];
  for (int j = beg; j < end; ++j){
    int s = col[j];
    a0 += h2[(size_t)s*2];
    a1 += h2[(size_t)s*2+1];
  }
  float dv = dinv[d];
  out[(size_t)d*2]   = fmaf(a0, dv, b[0]);
  out[(size_t)d*2+1] = fmaf(a1, dv, b[1]);
}

// ---------------- standalone dropout (fallback path only) ----------------
__global__ void k_dropout(const float* __restrict__ last, float* __restrict__ xemb){
  unsigned i = blockIdx.x*256 + threadIdx.x;
  if (i >= NF) return;
  xemb[i] = dropout_val(last[i], i);
}

// ======== fallback (atomic scatter) kernels ========
__global__ void k_convinit(const float* __restrict__ h, const float* __restrict__ dinv,
                           const float* __restrict__ b, float* __restrict__ out){
  int i = blockIdx.x*256 + threadIdx.x;
  if (i >= NF) return;
  int v = i >> 6, c = i & 63;
  float dv = dinv[v];
  out[i] = h[i]*dv*dv + b[c];
}
__global__ void k_scatter64(const int* __restrict__ src, const int* __restrict__ dst, int ne,
                            const float* __restrict__ h, const float* __restrict__ dinv,
                            float* __restrict__ out){
  int lane = threadIdx.x & 63;
  int wid  = (blockIdx.x*256 + threadIdx.x) >> 6;
  int nw   = (gridDim.x*256) >> 6;
  for (int e = wid; e < ne; e += nw){
    int s = src[e], d = dst[e];
    float coef = dinv[s]*dinv[d];
    atomicAdd(&out[d*64 + lane], h[s*64 + lane]*coef);
  }
}
__global__ void k_layeragg(const int* __restrict__ recv, const int* __restrict__ srcn, int ne,
                           const float* __restrict__ last, float* __restrict__ acc){
  int lane = threadIdx.x & 63;
  int wid  = (blockIdx.x*256 + threadIdx.x) >> 6;
  int nw   = (gridDim.x*256) >> 6;
  for (int e = wid; e < ne; e += nw){
    int r = recv[e], s = srcn[e];
    atomicAdd(&acc[r*64 + lane], last[s*64 + lane]);
  }
}
__global__ void k_scale(const float* __restrict__ in, const float* __restrict__ ds, int dsidx,
                        float* __restrict__ out){
  int i = blockIdx.x*256 + threadIdx.x;
  if (i < NF) out[i] = in[i] / ds[dsidx];
}
__global__ void k_convinit2(const float* __restrict__ h2, const float* __restrict__ dinv,
                            const float* __restrict__ b, float* __restrict__ out){
  int i = blockIdx.x*256 + threadIdx.x;
  if (i >= NN*2) return;
  int v = i >> 1, c = i & 1;
  float dv = dinv[v];
  out[i] = h2[i]*dv*dv + b[c];
}
__global__ void k_scatter2(const int* __restrict__ src, const int* __restrict__ dst, int ne,
                           const float* __restrict__ h2, const float* __restrict__ dinv,
                           float* __restrict__ out){
  int e = blockIdx.x*256 + threadIdx.x;
  if (e >= ne) return;
  int s = src[e], d = dst[e];
  float coef = dinv[s]*dinv[d];
  atomicAdd(&out[d*2 + 0], h2[s*2 + 0]*coef);
  atomicAdd(&out[d*2 + 1], h2[s*2 + 1]*coef);
}

extern "C" void kernel_launch(void* const* d_in, const int* in_sizes, int n_in,
                              void* d_out, int out_size, void* d_ws, size_t ws_size,
                              hipStream_t stream) {
  const float* x    = (const float*)d_in[0];
  const int*   ei   = (const int*)  d_in[1];
  const int*   lei  = (const int*)  d_in[2];
  const float* degs = (const float*)d_in[3];
  const float* lW1  = (const float*)d_in[4];
  const float* lb1  = (const float*)d_in[5];
  const float* lW2  = (const float*)d_in[6];
  const float* lb2  = (const float*)d_in[7];
  const float* pW1  = (const float*)d_in[8];
  const float* pb1  = (const float*)d_in[9];
  const float* pW2  = (const float*)d_in[10];
  const float* pb2  = (const float*)d_in[11];
  float* out = (float*)d_out;

  const int gN  = (NN + 255)/256;
  const int gE  = (EE + 255)/256;
  const int gEL = (ELL + 255)/256;
  const int gNF = (NF + 255)/256;
  const int gG16 = (NN*16 + 255)/256;   // 6250

  const bool dual   = ws_size >= (size_t)WS_DUAL * 4;
  const bool single = ws_size >= (size_t)WS_SINGLE * 4;

  if (dual) {
    float* base   = (float*)d_ws;
    float* dinv   = base;
    int*   cnt    = (int*)(base + OFF_CNT);
    int*   bsum   = (int*)(base + OFF_BSUM);
    int*   flag   = bsum + 120;
    int*   rpA    = (int*)(base + OFF_RPA);
    int*   colA   = (int*)(base + OFF_COLA);
    int*   rpB    = (int*)(base + OFF_RPB);
    int*   colB   = (int*)(base + OFF_COLB);
    float* F0     = base + OFF_COLB + 1000000;
    float* F1     = F0 + NF;
    float* F2     = F1 + NF;
    uint2* H0     = (uint2*)(F2 + NF);
    uint2* H1     = H0 + (size_t)NN*16;
    uint2* H2     = H1 + (size_t)NN*16;
    uint2* H3     = H2 + (size_t)NN*16;

    auto build_csr = [&](const int* srcp, const int* dstp, int ne, int gEdges, int computeDinv,
                         int* rowptr, int* col, int* rank){
      k_degrank<<<gEdges, 256, 0, stream>>>(dstp, ne, cnt, rank);
      k_scanfused<<<NB_SCAN, 1024, 0, stream>>>(cnt, bsum, flag, rowptr, dinv, computeDinv, NN);
      k_fillrz<<<gEdges, 256, 0, stream>>>(srcp, dstp, ne, rowptr, rank, col, cnt, flag);
    };

    const int* s0 = ei;                  const int* d0 = s0 + EE;
    const int* s1 = ei + 2*(size_t)EE;   const int* d1 = s1 + EE;
    const int* s2 = ei + 4*(size_t)EE;   const int* d2 = s2 + EE;
    const int* r0 = lei;                 const int* ls0 = r0 + ELL;
    const int* r1 = lei + 2*(size_t)ELL; const int* ls1 = r1 + ELL;

    k_zerof<<<gN, 256, 0, stream>>>(cnt, NN, flag);

    // ---- surface 0 ----
    build_csr(s0, d0, EE, gE, 1, rpA, colA, (int*)F0);
    k_gemm64h<false><<<6250, 256, 0, stream>>>(x, lW1, dinv, NN, H0);
    k_gathergemmh<<<6250, 256, 0, stream>>>(rpA, colA, H0, dinv, lb1, lW2, H1);
    k_gather64hh<<<gG16, 256, 0, stream>>>(rpA, colA, H1, dinv, lb2, H2);            // last16 = H2
    // ---- surface 1 ----
    build_csr(s1, d1, EE, gE, 1, rpA, colA, (int*)F0);
    build_csr(ls0, r0, ELL, gEL, 0, rpB, colB, (int*)F0);
    k_gemm64h<false><<<6250, 256, 0, stream>>>(x + (size_t)NF, lW1 + 4096, dinv, NN, H0);
    k_gathergemmh<<<6250, 256, 0, stream>>>(rpA, colA, H0, dinv, lb1 + 64, lW2 + 4096, H1);
    k_gatherlfagg2h<false,true><<<gG16, 256, 0, stream>>>(rpA, colA, H1, dinv, lb2 + 64,
                                                          rpB, colB, H2, degs, 0, (void*)H3);  // last16 = H3
    // ---- surface 2 ----
    build_csr(s2, d2, EE, gE, 1, rpA, colA, (int*)F0);
    build_csr(ls1, r1, ELL, gEL, 0, rpB, colB, (int*)F0);
    k_gemm64h<false><<<6250, 256, 0, stream>>>(x + 2*(size_t)NF, lW1 + 8192, dinv, NN, H0);
    k_gathergemmh<<<6250, 256, 0, stream>>>(rpA, colA, H0, dinv, lb1 + 128, lW2 + 8192, H1);
    k_gatherlfagg2h<true,false><<<gG16, 256, 0, stream>>>(rpA, colA, H1, dinv, lb2 + 128,
                                                          rpB, colB, H3, degs, 1, (void*)F1); // F1 = x_emb f32
    // ---- predictor (CSR-A = surface-2 edges; dinv = surface-2 degrees) ----
    k_gemm64h<false><<<6250, 256, 0, stream>>>(F1, pW1, dinv, NN, H0);
    k_predgather2h<<<gG16, 256, 0, stream>>>(rpA, colA, H0, dinv, pb1, pW2, F2);     // F2 = h2' [N,2]
    k_gather2<<<gN, 256, 0, stream>>>(rpA, colA, F2, dinv, pb2, out);
    k_probe<<<1, 64, 0, stream>>>(ei, 0u, out);
    return;
  }

  if (single) {
    float* base   = (float*)d_ws;
    float* dinv   = base;
    int*   cnt    = (int*)(base + OFF_CNT);
    int*   bsum   = (int*)(base + OFF_BSUM);
    int*   flag   = bsum + 120;
    int*   rpA    = (int*)(base + OFF_RPA);
    int*   colA   = (int*)(base + OFF_COLA);
    float* F0     = base + OFF_RPB;
    float* F1     = F0 + NF;
    float* F2     = F1 + NF;

    auto build_csr = [&](const int* srcp, const int* dstp, int ne, int gEdges, int computeDinv,
                         int* rowptr, int* col, int* rank){
      k_zerof<<<gN, 256, 0, stream>>>(cnt, NN, flag);
      k_degrank<<<gEdges, 256, 0, stream>>>(dstp, ne, cnt, rank);
      k_scanfused<<<NB_SCAN, 1024, 0, stream>>>(cnt, bsum, flag, rowptr, dinv, computeDinv, NN);
      k_fillr<<<gEdges, 256, 0, stream>>>(srcp, dstp, ne, rowptr, rank, col);
    };

    const int* s0 = ei;                  const int* d0 = s0 + EE;
    const int* s1 = ei + 2*(size_t)EE;   const int* d1 = s1 + EE;
    const int* s2 = ei + 4*(size_t)EE;   const int* d2 = s2 + EE;
    const int* r0 = lei;                 const int* ls0 = r0 + ELL;
    const int* r1 = lei + 2*(size_t)ELL; const int* ls1 = r1 + ELL;

    build_csr(s0, d0, EE, gE, 1, rpA, colA, (int*)F0);
    k_gemm64<false,true><<<6250, 256, 0, stream>>>(x, lW1, dinv, NN, F0);
    k_gathergemm<<<6250, 256, 0, stream>>>(rpA, colA, F0, dinv, lb1, lW2, F1);
    k_gather64<<<gG16, 256, 0, stream>>>(rpA, colA, F1, dinv, lb2, F2);
    build_csr(s1, d1, EE, gE, 1, rpA, colA, (int*)F0);
    k_gemm64<false,true><<<6250, 256, 0, stream>>>(x + (size_t)NF, lW1 + 4096, dinv, NN, F0);
    k_gathergemm<<<6250, 256, 0, stream>>>(rpA, colA, F0, dinv, lb1 + 64, lW2 + 4096, F1);
    build_csr(ls0, r0, ELL, gEL, 0, rpA, colA, (int*)F0);
    k_agggather<false><<<gG16, 256, 0, stream>>>(rpA, colA, F1, F2, degs, 0, F0);
    build_csr(s2, d2, EE, gE, 1, rpA, colA, (int*)F1);
    k_gemm64<false,true><<<6250, 256, 0, stream>>>(x + 2*(size_t)NF, lW1 + 8192, dinv, NN, F1);
    k_gathergemm<<<6250, 256, 0, stream>>>(rpA, colA, F1, dinv, lb1 + 128, lW2 + 8192, F2);
    build_csr(ls1, r1, ELL, gEL, 0, rpA, colA, (int*)F1);
    k_agggather<true><<<gG16, 256, 0, stream>>>(rpA, colA, F2, F0, degs, 1, F1);
    build_csr(s2, d2, EE, gE, 0, rpA, colA, (int*)F0);
    k_gemm64<false,true><<<6250, 256, 0, stream>>>(F1, pW1, dinv, NN, F0);
    k_gather64<<<gG16, 256, 0, stream>>>(rpA, colA, F0, dinv, pb1, F2);
    k_gemm2<true,true><<<gN, 256, 0, stream>>>(F2, pW2, dinv, NN, F1);
    k_gather2<<<gN, 256, 0, stream>>>(rpA, colA, F1, dinv, pb2, out);
    k_probe<<<1, 64, 0, stream>>>(ei, 0u, out);
    return;
  }

  // ================= fallback: verified atomic-scatter path =================
  float* base = (float*)d_ws;
  float* dinv = base;
  int*   cnt  = (int*)(base + 100352);
  float* A    = base + 262144;
  float* B    = A + NF;
  float* C    = B + NF;

  for (int i = 0; i < 3; ++i){
    const int* srcp = ei + (size_t)i*2*EE;
    const int* dstp = srcp + EE;
    k_zero_int<<<gN, 256, 0, stream>>>(cnt, NN);
    k_deg<<<gE, 256, 0, stream>>>(dstp, EE, cnt);
    k_dinv<<<gN, 256, 0, stream>>>(cnt, dinv, NN);
    k_gemm64<false,false><<<6250, 256, 0, stream>>>(x + (size_t)i*NF, lW1 + (size_t)i*64*64, dinv, NN, A);
    k_convinit<<<gNF, 256, 0, stream>>>(A, dinv, lb1 + (size_t)i*64, B);
    k_scatter64<<<8192, 256, 0, stream>>>(srcp, dstp, EE, A, dinv, B);
    k_gemm64<true,false><<<6250, 256, 0, stream>>>(B, lW2 + (size_t)i*64*64, dinv, NN, A);
    float* T = (i == 0) ? C : B;
    k_convinit<<<gNF, 256, 0, stream>>>(A, dinv, lb2 + (size_t)i*64, T);
    k_scatter64<<<8192, 256, 0, stream>>>(srcp, dstp, EE, A, dinv, T);
    if (i > 0){
      const int* recvp = lei + (size_t)(i-1)*2*ELL;
      const int* lsrcp = recvp + ELL;
      k_layeragg<<<4096, 256, 0, stream>>>(recvp, lsrcp, ELL, C, B);
      k_scale<<<gNF, 256, 0, stream>>>(B, degs, i-1, C);
    }
  }
  k_dropout<<<gNF, 256, 0, stream>>>(C, B);
  const int* srcp = ei + (size_t)2*2*EE;
  const int* dstp = srcp + EE;
  k_gemm64<false,false><<<6250, 256, 0, stream>>>(B, pW1, dinv, NN, A);
  k_convinit<<<gNF, 256, 0, stream>>>(A, dinv, pb1, C);
  k_scatter64<<<8192, 256, 0, stream>>>(srcp, dstp, EE, A, dinv, C);
  k_gemm2<true,false><<<gN, 256, 0, stream>>>(C, pW2, dinv, NN, B);
  k_convinit2<<<(NN*2 + 255)/256, 256, 0, stream>>>(B, dinv, pb2, out);
  k_scatter2<<<gE, 256, 0, stream>>>(srcp, dstp, EE, B, dinv, out);
  k_probe<<<1, 64, 0, stream>>>(ei, 0u, out);
}

// Round 19
// 626.558 us; speedup vs baseline: 1.0084x; 1.0084x over previous
//
#include <hip/hip_runtime.h>
#include <hip/hip_fp16.h>

#define NN 100000
#define EE 1000000
#define ELL 500000
#define NF (NN*64)
#define NB_SCAN ((NN + 1023) / 1024)   // 98

// ws layouts (floats)
#define OFF_CNT    100352
#define OFF_BSUM   200704
#define OFF_RPA    200832
#define OFF_COLA   301184
#define OFF_RPB    1301184
#define OFF_COLB   1401536
#define WS_SINGLE  (1301184 + 3*NF)              // 82.0 MB
#define WS_DUAL    (2401536 + 5*NF)              // 137.6 MB

// ---------------- Threefry-2x32 ----------------
__device__ __forceinline__ void threefry2x32(unsigned k0, unsigned k1, unsigned &x0, unsigned &x1){
  unsigned ks2 = k0 ^ k1 ^ 0x1BD11BDAu;
#define TF_R(R) { x0 += x1; x1 = (x1<<(R))|(x1>>(32-(R))); x1 ^= x0; }
  x0 += k0; x1 += k1;
  TF_R(13) TF_R(15) TF_R(26) TF_R(6)
  x0 += k1;  x1 += ks2 + 1u;
  TF_R(17) TF_R(29) TF_R(16) TF_R(24)
  x0 += ks2; x1 += k0 + 2u;
  TF_R(13) TF_R(15) TF_R(26) TF_R(6)
  x0 += k0;  x1 += k1 + 3u;
  TF_R(17) TF_R(29) TF_R(16) TF_R(24)
  x0 += k1;  x1 += ks2 + 4u;
  TF_R(13) TF_R(15) TF_R(26) TF_R(6)
  x0 += ks2; x1 += k0 + 5u;
#undef TF_R
}

__device__ __forceinline__ float dropout_val(float v, unsigned i){
  unsigned x0 = 0u, x1 = i;
  threefry2x32(0u, 42u, x0, x1);
  unsigned bits = x0 ^ x1;
  float u = __uint_as_float((bits >> 9) | 0x3f800000u) - 1.0f;
  return (u < 0.6f) ? v * (1.0f/0.6f) : 0.0f;
}

__global__ void k_probe(const int* __restrict__ ei, unsigned hostbits, float* __restrict__ out){
  if (threadIdx.x != 0 || blockIdx.x != 0) return;
  unsigned bits = hostbits;
  { unsigned a=0u, b=0u; threefry2x32(0u, 0u, a, b);
    if (a != 0x6b200159u || b != 0x99ba4efeu) bits |= 1u; }
  if (bits) out[0] = 1.0e4f * (float)bits;
}

// ---------------- fp16 pack/unpack ----------------
__device__ __forceinline__ uint2 f4_to_h4(float4 v){
  __half2 lo = __floats2half2_rn(v.x, v.y);
  __half2 hi = __floats2half2_rn(v.z, v.w);
  uint2 r; r.x = *(unsigned*)&lo; r.y = *(unsigned*)&hi; return r;
}
__device__ __forceinline__ float4 h4_to_f4(uint2 u){
  __half2 lo = *(__half2*)&u.x;
  __half2 hi = *(__half2*)&u.y;
  float2 a = __half22float2(lo), b = __half22float2(hi);
  return make_float4(a.x, a.y, b.x, b.y);
}

// ---------------- utility ----------------
__global__ void k_zero_int(int* __restrict__ p, int n){
  int i = blockIdx.x*256 + threadIdx.x;
  if (i < n) p[i] = 0;
}

__global__ void k_zerof(int* __restrict__ cnt, int n, int* __restrict__ flag){
  int i = blockIdx.x*256 + threadIdx.x;
  if (i < n) cnt[i] = 0;
  if (i == 0) *flag = 0;
}

__global__ void k_deg(const int* __restrict__ dst, int ne, int* __restrict__ cnt){
  int i = blockIdx.x*256 + threadIdx.x;
  if (i < ne) atomicAdd(&cnt[dst[i]], 1);
}

__global__ void k_degrank(const int* __restrict__ dst, int ne, int* __restrict__ cnt,
                          int* __restrict__ rank){
  int i = blockIdx.x*256 + threadIdx.x;
  if (i >= ne) return;
  rank[i] = atomicAdd(&cnt[dst[i]], 1);
}

__global__ void k_dinv(const int* __restrict__ cnt, float* __restrict__ dinv, int n){
  int i = blockIdx.x*256 + threadIdx.x;
  if (i < n) dinv[i] = 1.0f / sqrtf((float)(cnt[i] + 1));
}

// ---------------- fused single-launch scan (98 blocks, device spin barrier) + dinv ----------------
__global__ __launch_bounds__(1024) void k_scanfused(const int* __restrict__ cnt, int* __restrict__ bsum,
                                                    int* __restrict__ flag, int* __restrict__ rowptr,
                                                    float* __restrict__ dinv, int computeDinv, int n){
  __shared__ int lds[1024];
  __shared__ int ps[128];
  int t = threadIdx.x;
  int i = blockIdx.x*1024 + t;
  int v = (i < n) ? cnt[i] : 0;
  if (computeDinv && i < n) dinv[i] = 1.0f / sqrtf((float)(v + 1));
  lds[t] = v;
  __syncthreads();
  for (int off = 1; off < 1024; off <<= 1){
    int x = (t >= off) ? lds[t - off] : 0;
    __syncthreads();
    lds[t] += x;
    __syncthreads();
  }
  int incl = lds[t];
  if (t == 1023){
    bsum[blockIdx.x] = lds[1023];
    __threadfence();
    atomicAdd(flag, 1);
  }
  if (t == 0){
    while (atomicAdd(flag, 0) < NB_SCAN) { }
  }
  __syncthreads();
  if (t < 128) ps[t] = (t < blockIdx.x) ? bsum[t] : 0;
  __syncthreads();
  if (t < 64) ps[t] += ps[t + 64];
  __syncthreads();
  if (t < 32) ps[t] += ps[t + 32];
  __syncthreads();
  if (t < 16) ps[t] += ps[t + 16];
  __syncthreads();
  if (t < 8)  ps[t] += ps[t + 8];
  __syncthreads();
  if (t < 4)  ps[t] += ps[t + 4];
  __syncthreads();
  if (t < 2)  ps[t] += ps[t + 2];
  __syncthreads();
  if (t < 1)  ps[t] += ps[t + 1];
  __syncthreads();
  int excl = incl - v + ps[0];
  if (i < n)  rowptr[i] = excl;
  if (i == n-1) rowptr[n] = excl + v;
}

// ---------------- CSR fill, atomic-free; also re-zeroes cnt+flag for the NEXT build ----------------
__global__ void k_fillrz(const int* __restrict__ src, const int* __restrict__ dst, int ne,
                         const int* __restrict__ rowptr, const int* __restrict__ rank,
                         int* __restrict__ col, int* __restrict__ cnt, int* __restrict__ flag){
  int e = blockIdx.x*256 + threadIdx.x;
  if (e < NN) cnt[e] = 0;
  if (e == 0) *flag = 0;
  if (e >= ne) return;
  col[rowptr[dst[e]] + rank[e]] = src[e];
}

__global__ void k_fillr(const int* __restrict__ src, const int* __restrict__ dst, int ne,
                        const int* __restrict__ rowptr, const int* __restrict__ rank,
                        int* __restrict__ col){
  int e = blockIdx.x*256 + threadIdx.x;
  if (e >= ne) return;
  col[rowptr[dst[e]] + rank[e]] = src[e];
}

// ---------------- GEMM [nrows,64] @ [64,64]; f32 out ----------------
template<bool RELU, bool SCALE>
__global__ __launch_bounds__(256) void k_gemm64(const float* __restrict__ X, const float* __restrict__ W,
                                                const float* __restrict__ dinv,
                                                int nrows, float* __restrict__ Y){
  __shared__ float Ws[64][64];
  int t = threadIdx.x;
  {
    const float4* W4 = (const float4*)W;
    float4* S4 = (float4*)&Ws[0][0];
    #pragma unroll
    for (int i = 0; i < 4; ++i) S4[t + 256*i] = W4[t + 256*i];
  }
  __syncthreads();
  int row = blockIdx.x*16 + (t>>4);
  if (row >= nrows) return;
  int c0 = (t & 15) * 4;
  const float4* Xr = (const float4*)(X + (size_t)row*64);
  float4 acc = make_float4(0.f,0.f,0.f,0.f);
  #pragma unroll
  for (int kk = 0; kk < 16; ++kk){
    float4 xv = Xr[kk];
    if (RELU){
      xv.x = fmaxf(xv.x, 0.f); xv.y = fmaxf(xv.y, 0.f);
      xv.z = fmaxf(xv.z, 0.f); xv.w = fmaxf(xv.w, 0.f);
    }
    int k = kk*4;
    float4 w0 = *(const float4*)&Ws[k+0][c0];
    float4 w1 = *(const float4*)&Ws[k+1][c0];
    float4 w2 = *(const float4*)&Ws[k+2][c0];
    float4 w3 = *(const float4*)&Ws[k+3][c0];
    acc.x = fmaf(xv.x, w0.x, acc.x); acc.y = fmaf(xv.x, w0.y, acc.y);
    acc.z = fmaf(xv.x, w0.z, acc.z); acc.w = fmaf(xv.x, w0.w, acc.w);
    acc.x = fmaf(xv.y, w1.x, acc.x); acc.y = fmaf(xv.y, w1.y, acc.y);
    acc.z = fmaf(xv.y, w1.z, acc.z); acc.w = fmaf(xv.y, w1.w, acc.w);
    acc.x = fmaf(xv.z, w2.x, acc.x); acc.y = fmaf(xv.z, w2.y, acc.y);
    acc.z = fmaf(xv.z, w2.z, acc.z); acc.w = fmaf(xv.z, w2.w, acc.w);
    acc.x = fmaf(xv.w, w3.x, acc.x); acc.y = fmaf(xv.w, w3.y, acc.y);
    acc.z = fmaf(xv.w, w3.z, acc.z); acc.w = fmaf(xv.w, w3.w, acc.w);
  }
  if (SCALE){
    float dv = dinv[row];
    acc.x *= dv; acc.y *= dv; acc.z *= dv; acc.w *= dv;
  }
  *(float4*)(Y + (size_t)row*64 + c0) = acc;
}

// ---------------- GEMM f32-in -> fp16 table out ----------------
template<bool RELU>
__global__ __launch_bounds__(256) void k_gemm64h(const float* __restrict__ X, const float* __restrict__ W,
                                                 const float* __restrict__ dinv,
                                                 int nrows, uint2* __restrict__ Y16){
  __shared__ float Ws[64][64];
  int t = threadIdx.x;
  {
    const float4* W4 = (const float4*)W;
    float4* S4 = (float4*)&Ws[0][0];
    #pragma unroll
    for (int i = 0; i < 4; ++i) S4[t + 256*i] = W4[t + 256*i];
  }
  __syncthreads();
  int row = blockIdx.x*16 + (t>>4);
  if (row >= nrows) return;
  int c0 = (t & 15) * 4;
  const float4* Xr = (const float4*)(X + (size_t)row*64);
  float4 acc = make_float4(0.f,0.f,0.f,0.f);
  #pragma unroll
  for (int kk = 0; kk < 16; ++kk){
    float4 xv = Xr[kk];
    if (RELU){
      xv.x = fmaxf(xv.x, 0.f); xv.y = fmaxf(xv.y, 0.f);
      xv.z = fmaxf(xv.z, 0.f); xv.w = fmaxf(xv.w, 0.f);
    }
    int k = kk*4;
    float4 w0 = *(const float4*)&Ws[k+0][c0];
    float4 w1 = *(const float4*)&Ws[k+1][c0];
    float4 w2 = *(const float4*)&Ws[k+2][c0];
    float4 w3 = *(const float4*)&Ws[k+3][c0];
    acc.x = fmaf(xv.x, w0.x, acc.x); acc.y = fmaf(xv.x, w0.y, acc.y);
    acc.z = fmaf(xv.x, w0.z, acc.z); acc.w = fmaf(xv.x, w0.w, acc.w);
    acc.x = fmaf(xv.y, w1.x, acc.x); acc.y = fmaf(xv.y, w1.y, acc.y);
    acc.z = fmaf(xv.y, w1.z, acc.z); acc.w = fmaf(xv.y, w1.w, acc.w);
    acc.x = fmaf(xv.z, w2.x, acc.x); acc.y = fmaf(xv.z, w2.y, acc.y);
    acc.z = fmaf(xv.z, w2.z, acc.z); acc.w = fmaf(xv.z, w2.w, acc.w);
    acc.x = fmaf(xv.w, w3.x, acc.x); acc.y = fmaf(xv.w, w3.y, acc.y);
    acc.z = fmaf(xv.w, w3.z, acc.z); acc.w = fmaf(xv.w, w3.w, acc.w);
  }
  float dv = dinv[row];
  acc.x *= dv; acc.y *= dv; acc.z *= dv; acc.w *= dv;
  Y16[(size_t)row*16 + (t & 15)] = f4_to_h4(acc);
}

// ---------------- GEMM [nrows,64] @ [64,2] ----------------
template<bool RELU, bool SCALE>
__global__ __launch_bounds__(256) void k_gemm2(const float* __restrict__ X, const float* __restrict__ W,
                                               const float* __restrict__ dinv,
                                               int nrows, float* __restrict__ Y){
  __shared__ float Ws[128];
  int t = threadIdx.x;
  if (t < 128) Ws[t] = W[t];
  __syncthreads();
  int row = blockIdx.x*256 + t;
  if (row >= nrows) return;
  const float4* Xr = (const float4*)(X + (size_t)row*64);
  float a0 = 0.f, a1 = 0.f;
  #pragma unroll
  for (int kk = 0; kk < 16; ++kk){
    float4 xv = Xr[kk];
    if (RELU){ xv.x=fmaxf(xv.x,0.f); xv.y=fmaxf(xv.y,0.f); xv.z=fmaxf(xv.z,0.f); xv.w=fmaxf(xv.w,0.f); }
    int k = kk*4;
    a0 = fmaf(xv.x, Ws[2*k+0], a0); a1 = fmaf(xv.x, Ws[2*k+1], a1);
    a0 = fmaf(xv.y, Ws[2*k+2], a0); a1 = fmaf(xv.y, Ws[2*k+3], a1);
    a0 = fmaf(xv.z, Ws[2*k+4], a0); a1 = fmaf(xv.z, Ws[2*k+5], a1);
    a0 = fmaf(xv.w, Ws[2*k+6], a0); a1 = fmaf(xv.w, Ws[2*k+7], a1);
  }
  if (SCALE){ float dv = dinv[row]; a0 *= dv; a1 *= dv; }
  Y[(size_t)row*2]   = a0;
  Y[(size_t)row*2+1] = a1;
}

// ---------------- pipelined row-gather helpers ----------------
__device__ __forceinline__ float4 gather_rows4(const int* __restrict__ col, int beg, int end,
                                               const float4* __restrict__ h4, int fq, float4 acc){
  int j = beg;
  bool p0 = j   < end; int c0 = p0 ? col[j]   : 0;
  bool p1 = j+1 < end; int c1 = p1 ? col[j+1] : 0;
  bool p2 = j+2 < end; int c2 = p2 ? col[j+2] : 0;
  bool p3 = j+3 < end; int c3 = p3 ? col[j+3] : 0;
  while (p0){
    float4 v0 = h4[(size_t)c0*16 + fq];
    float4 v1 = p1 ? h4[(size_t)c1*16 + fq] : make_float4(0.f,0.f,0.f,0.f);
    float4 v2 = p2 ? h4[(size_t)c2*16 + fq] : make_float4(0.f,0.f,0.f,0.f);
    float4 v3 = p3 ? h4[(size_t)c3*16 + fq] : make_float4(0.f,0.f,0.f,0.f);
    j += 4;
    bool q0 = j < end, q1 = j+1 < end, q2 = j+2 < end, q3 = j+3 < end;
    int n0 = q0 ? col[j]   : 0;
    int n1 = q1 ? col[j+1] : 0;
    int n2 = q2 ? col[j+2] : 0;
    int n3 = q3 ? col[j+3] : 0;
    acc.x += v0.x + v1.x + v2.x + v3.x;
    acc.y += v0.y + v1.y + v2.y + v3.y;
    acc.z += v0.z + v1.z + v2.z + v3.z;
    acc.w += v0.w + v1.w + v2.w + v3.w;
    p0=q0; p1=q1; p2=q2; p3=q3; c0=n0; c1=n1; c2=n2; c3=n3;
  }
  return acc;
}

// 8-deep pipelined fp16 gather; packed-half2 accumulation, f32 flush per 8-edge iteration
__device__ __forceinline__ float4 gather_rows8_h16(const int* __restrict__ col, int beg, int end,
                                                   const uint2* __restrict__ h16, int fq, float4 acc){
  const uint2 z = make_uint2(0u, 0u);
  int j = beg;
  bool p0 = j   < end; int c0 = p0 ? col[j]   : 0;
  bool p1 = j+1 < end; int c1 = p1 ? col[j+1] : 0;
  bool p2 = j+2 < end; int c2 = p2 ? col[j+2] : 0;
  bool p3 = j+3 < end; int c3 = p3 ? col[j+3] : 0;
  bool p4 = j+4 < end; int c4 = p4 ? col[j+4] : 0;
  bool p5 = j+5 < end; int c5 = p5 ? col[j+5] : 0;
  bool p6 = j+6 < end; int c6 = p6 ? col[j+6] : 0;
  bool p7 = j+7 < end; int c7 = p7 ? col[j+7] : 0;
  while (p0){
    uint2 u0 = h16[(size_t)c0*16 + fq];
    uint2 u1 = p1 ? h16[(size_t)c1*16 + fq] : z;
    uint2 u2 = p2 ? h16[(size_t)c2*16 + fq] : z;
    uint2 u3 = p3 ? h16[(size_t)c3*16 + fq] : z;
    uint2 u4 = p4 ? h16[(size_t)c4*16 + fq] : z;
    uint2 u5 = p5 ? h16[(size_t)c5*16 + fq] : z;
    uint2 u6 = p6 ? h16[(size_t)c6*16 + fq] : z;
    uint2 u7 = p7 ? h16[(size_t)c7*16 + fq] : z;
    j += 8;
    bool q0 = j   < end, q1 = j+1 < end, q2 = j+2 < end, q3 = j+3 < end;
    bool q4 = j+4 < end, q5 = j+5 < end, q6 = j+6 < end, q7 = j+7 < end;
    int n0 = q0 ? col[j]   : 0;
    int n1 = q1 ? col[j+1] : 0;
    int n2 = q2 ? col[j+2] : 0;
    int n3 = q3 ? col[j+3] : 0;
    int n4 = q4 ? col[j+4] : 0;
    int n5 = q5 ? col[j+5] : 0;
    int n6 = q6 ? col[j+6] : 0;
    int n7 = q7 ? col[j+7] : 0;
    // packed-half2 accumulation of this iteration's <=8 rows (bounded partial sum),
    // then one f32 flush -> master accumulator stays f32.
    __half2 s01 = __hadd2(*(__half2*)&u0.x, *(__half2*)&u1.x);
    __half2 s23 = __hadd2(*(__half2*)&u0.y, *(__half2*)&u1.y);
    __half2 t01 = __hadd2(*(__half2*)&u2.x, *(__half2*)&u3.x);
    __half2 t23 = __hadd2(*(__half2*)&u2.y, *(__half2*)&u3.y);
    s01 = __hadd2(s01, __hadd2(*(__half2*)&u4.x, *(__half2*)&u5.x));
    s23 = __hadd2(s23, __hadd2(*(__half2*)&u4.y, *(__half2*)&u5.y));
    t01 = __hadd2(t01, __hadd2(*(__half2*)&u6.x, *(__half2*)&u7.x));
    t23 = __hadd2(t23, __hadd2(*(__half2*)&u6.y, *(__half2*)&u7.y));
    float2 a = __half22float2(s01), b = __half22float2(t01);
    float2 c = __half22float2(s23), d = __half22float2(t23);
    acc.x += a.x + b.x;
    acc.y += a.y + b.y;
    acc.z += c.x + d.x;
    acc.w += c.y + d.y;
    p0=q0; p1=q1; p2=q2; p3=q3; p4=q4; p5=q5; p6=q6; p7=q7;
    c0=n0; c1=n1; c2=n2; c3=n3; c4=n4; c5=n5; c6=n6; c7=n7;
  }
  return acc;
}

// ---------------- CSR gather conv, f32 (single tier) ----------------
__global__ __launch_bounds__(256) void k_gather64(const int* __restrict__ rowptr, const int* __restrict__ col,
                                                  const float* __restrict__ h, const float* __restrict__ dinv,
                                                  const float* __restrict__ b, float* __restrict__ out){
  int gt = blockIdx.x*256 + threadIdx.x;
  int fq = gt & 15;
  int node = gt >> 4;
  if (node >= NN) return;
  const float4* __restrict__ h4 = (const float4*)h;
  float4 acc = h4[(size_t)node*16 + fq];
  acc = gather_rows4(col, rowptr[node], rowptr[node+1], h4, fq, acc);
  float dv = dinv[node];
  float4 bb = ((const float4*)b)[fq];
  float4 r;
  r.x = fmaf(acc.x, dv, bb.x); r.y = fmaf(acc.y, dv, bb.y);
  r.z = fmaf(acc.z, dv, bb.z); r.w = fmaf(acc.w, dv, bb.w);
  *(float4*)(out + (size_t)node*64 + fq*4) = r;
}

// ---------------- CSR gather conv, fp16 in -> fp16 out ----------------
__global__ __launch_bounds__(256) void k_gather64hh(const int* __restrict__ rowptr, const int* __restrict__ col,
                                                    const uint2* __restrict__ h16, const float* __restrict__ dinv,
                                                    const float* __restrict__ b, uint2* __restrict__ out16){
  int gt = blockIdx.x*256 + threadIdx.x;
  int fq = gt & 15;
  int node = gt >> 4;
  if (node >= NN) return;
  float4 acc = h4_to_f4(h16[(size_t)node*16 + fq]);
  acc = gather_rows8_h16(col, rowptr[node], rowptr[node+1], h16, fq, acc);
  float dv = dinv[node];
  float4 bb = ((const float4*)b)[fq];
  float4 r;
  r.x = fmaf(acc.x, dv, bb.x); r.y = fmaf(acc.y, dv, bb.y);
  r.z = fmaf(acc.z, dv, bb.z); r.w = fmaf(acc.w, dv, bb.w);
  out16[(size_t)node*16 + fq] = f4_to_h4(r);
}

// ---------------- FUSED: gather conv1(fp16) + ReLU + @W2 + scale -> fp16 table ----------------
__global__ __launch_bounds__(256) void k_gathergemmh(const int* __restrict__ rowptr, const int* __restrict__ col,
                                                     const uint2* __restrict__ h16, const float* __restrict__ dinv,
                                                     const float* __restrict__ b1, const float* __restrict__ W2,
                                                     uint2* __restrict__ Y16){
  __shared__ float Ws[64][64];
  __shared__ float rows[16][68];
  int t = threadIdx.x;
  {
    const float4* W4 = (const float4*)W2;
    float4* S4 = (float4*)&Ws[0][0];
    #pragma unroll
    for (int i = 0; i < 4; ++i) S4[t + 256*i] = W4[t + 256*i];
  }
  __syncthreads();
  int fq = t & 15, grp = t >> 4;
  int node = blockIdx.x*16 + grp;
  bool alive = node < NN;
  float dv = 0.f;
  if (alive){
    float4 acc = h4_to_f4(h16[(size_t)node*16 + fq]);
    acc = gather_rows8_h16(col, rowptr[node], rowptr[node+1], h16, fq, acc);
    dv = dinv[node];
    float4 bb = ((const float4*)b1)[fq];
    float4 r;
    r.x = fmaxf(fmaf(acc.x, dv, bb.x), 0.f);
    r.y = fmaxf(fmaf(acc.y, dv, bb.y), 0.f);
    r.z = fmaxf(fmaf(acc.z, dv, bb.z), 0.f);
    r.w = fmaxf(fmaf(acc.w, dv, bb.w), 0.f);
    *(float4*)&rows[grp][fq*4] = r;
  }
  __syncthreads();
  if (alive){
    const float* __restrict__ row = &rows[grp][0];
    float4 o = make_float4(0.f,0.f,0.f,0.f);
    int c0 = fq*4;
    #pragma unroll 8
    for (int k = 0; k < 64; ++k){
      float rv = row[k];
      float4 w = *(const float4*)&Ws[k][c0];
      o.x = fmaf(rv, w.x, o.x); o.y = fmaf(rv, w.y, o.y);
      o.z = fmaf(rv, w.z, o.z); o.w = fmaf(rv, w.w, o.w);
    }
    o.x *= dv; o.y *= dv; o.z *= dv; o.w *= dv;
    Y16[(size_t)node*16 + fq] = f4_to_h4(o);
  }
}

// f32 version (single tier)
__global__ __launch_bounds__(256) void k_gathergemm(const int* __restrict__ rowptr, const int* __restrict__ col,
                                                    const float* __restrict__ h, const float* __restrict__ dinv,
                                                    const float* __restrict__ b1, const float* __restrict__ W2,
                                                    float* __restrict__ Y){
  __shared__ float Ws[64][64];
  __shared__ float rows[16][68];
  int t = threadIdx.x;
  {
    const float4* W4 = (const float4*)W2;
    float4* S4 = (float4*)&Ws[0][0];
    #pragma unroll
    for (int i = 0; i < 4; ++i) S4[t + 256*i] = W4[t + 256*i];
  }
  __syncthreads();
  int fq = t & 15, grp = t >> 4;
  int node = blockIdx.x*16 + grp;
  bool alive = node < NN;
  float dv = 0.f;
  if (alive){
    const float4* __restrict__ h4 = (const float4*)h;
    float4 acc = h4[(size_t)node*16 + fq];
    acc = gather_rows4(col, rowptr[node], rowptr[node+1], h4, fq, acc);
    dv = dinv[node];
    float4 bb = ((const float4*)b1)[fq];
    float4 r;
    r.x = fmaxf(fmaf(acc.x, dv, bb.x), 0.f);
    r.y = fmaxf(fmaf(acc.y, dv, bb.y), 0.f);
    r.z = fmaxf(fmaf(acc.z, dv, bb.z), 0.f);
    r.w = fmaxf(fmaf(acc.w, dv, bb.w), 0.f);
    *(float4*)&rows[grp][fq*4] = r;
  }
  __syncthreads();
  if (alive){
    const float* __restrict__ row = &rows[grp][0];
    float4 o = make_float4(0.f,0.f,0.f,0.f);
    int c0 = fq*4;
    #pragma unroll 8
    for (int k = 0; k < 64; ++k){
      float rv = row[k];
      float4 w = *(const float4*)&Ws[k][c0];
      o.x = fmaf(rv, w.x, o.x); o.y = fmaf(rv, w.y, o.y);
      o.z = fmaf(rv, w.z, o.z); o.w = fmaf(rv, w.w, o.w);
    }
    o.x *= dv; o.y *= dv; o.z *= dv; o.w *= dv;
    *(float4*)(Y + (size_t)node*64 + fq*4) = o;
  }
}

// ---------------- FUSED: lf-gather (fp16, CSR-A) + cross-layer agg (fp16 last, CSR-B) + scale (+drop) ----------------
template<bool DROP, bool OUT16>
__global__ __launch_bounds__(256) void k_gatherlfagg2h(const int* __restrict__ rpA, const int* __restrict__ colA,
                                                       const uint2* __restrict__ h16, const float* __restrict__ dinv,
                                                       const float* __restrict__ b,
                                                       const int* __restrict__ rpB, const int* __restrict__ colB,
                                                       const uint2* __restrict__ last16,
                                                       const float* __restrict__ ds, int dsidx,
                                                       void* __restrict__ outv){
  int gt = blockIdx.x*256 + threadIdx.x;
  int fq = gt & 15;
  int node = gt >> 4;
  if (node >= NN) return;
  float4 acc = h4_to_f4(h16[(size_t)node*16 + fq]);
  acc = gather_rows8_h16(colA, rpA[node], rpA[node+1], h16, fq, acc);
  float dv = dinv[node];
  float4 bb = ((const float4*)b)[fq];
  float4 lf;
  lf.x = fmaf(acc.x, dv, bb.x); lf.y = fmaf(acc.y, dv, bb.y);
  lf.z = fmaf(acc.z, dv, bb.z); lf.w = fmaf(acc.w, dv, bb.w);
  float4 agg = gather_rows8_h16(colB, rpB[node], rpB[node+1], last16, fq,
                                make_float4(0.f,0.f,0.f,0.f));
  float inv = 1.0f / ds[dsidx];
  float4 r;
  r.x = (lf.x + agg.x) * inv; r.y = (lf.y + agg.y) * inv;
  r.z = (lf.z + agg.z) * inv; r.w = (lf.w + agg.w) * inv;
  if (DROP){
    unsigned base_i = (unsigned)node*64u + (unsigned)fq*4u;
    r.x = dropout_val(r.x, base_i + 0);
    r.y = dropout_val(r.y, base_i + 1);
    r.z = dropout_val(r.z, base_i + 2);
    r.w = dropout_val(r.w, base_i + 3);
  }
  if (OUT16) ((uint2*)outv)[(size_t)node*16 + fq] = f4_to_h4(r);
  else       *(float4*)((float*)outv + (size_t)node*64 + fq*4) = r;
}

// ---------------- CSR gather cross-layer agg f32 (single tier) ----------------
template<bool DROP>
__global__ __launch_bounds__(256) void k_agggather(const int* __restrict__ rowptr, const int* __restrict__ col,
                                                    const float* __restrict__ lf, const float* __restrict__ last,
                                                    const float* __restrict__ ds, int dsidx, float* __restrict__ out){
  int gt = blockIdx.x*256 + threadIdx.x;
  int fq = gt & 15;
  int node = gt >> 4;
  if (node >= NN) return;
  float4 acc = ((const float4*)lf)[(size_t)node*16 + fq];
  acc = gather_rows4(col, rowptr[node], rowptr[node+1], (const float4*)last, fq, acc);
  float inv = 1.0f / ds[dsidx];
  float4 r;
  r.x = acc.x * inv; r.y = acc.y * inv; r.z = acc.z * inv; r.w = acc.w * inv;
  if (DROP){
    unsigned base_i = (unsigned)node*64u + (unsigned)fq*4u;
    r.x = dropout_val(r.x, base_i + 0);
    r.y = dropout_val(r.y, base_i + 1);
    r.z = dropout_val(r.z, base_i + 2);
    r.w = dropout_val(r.w, base_i + 3);
  }
  *(float4*)(out + (size_t)node*64 + fq*4) = r;
}

// ---------------- FUSED predictor tail: gather(H0) + pb1 + relu + @pW2 + dv -> [N,2] ----------------
__global__ __launch_bounds__(256) void k_predgather2h(const int* __restrict__ rowptr, const int* __restrict__ col,
                                                      const uint2* __restrict__ h16, const float* __restrict__ dinv,
                                                      const float* __restrict__ b1, const float* __restrict__ W2,
                                                      float* __restrict__ Y){
  int gt = blockIdx.x*256 + threadIdx.x;
  int fq = gt & 15;
  int node = gt >> 4;
  if (node >= NN) return;
  float4 acc = h4_to_f4(h16[(size_t)node*16 + fq]);
  acc = gather_rows8_h16(col, rowptr[node], rowptr[node+1], h16, fq, acc);
  float dv = dinv[node];
  float4 bb = ((const float4*)b1)[fq];
  float4 r;
  r.x = fmaxf(fmaf(acc.x, dv, bb.x), 0.f);
  r.y = fmaxf(fmaf(acc.y, dv, bb.y), 0.f);
  r.z = fmaxf(fmaf(acc.z, dv, bb.z), 0.f);
  r.w = fmaxf(fmaf(acc.w, dv, bb.w), 0.f);
  const float4* w4 = (const float4*)W2;
  float4 wa = w4[fq*2], wb = w4[fq*2 + 1];
  float o0 = r.x*wa.x + r.y*wa.z + r.z*wb.x + r.w*wb.z;
  float o1 = r.x*wa.y + r.y*wa.w + r.z*wb.y + r.w*wb.w;
  o0 += __shfl_xor(o0, 1); o1 += __shfl_xor(o1, 1);
  o0 += __shfl_xor(o0, 2); o1 += __shfl_xor(o1, 2);
  o0 += __shfl_xor(o0, 4); o1 += __shfl_xor(o1, 4);
  o0 += __shfl_xor(o0, 8); o1 += __shfl_xor(o1, 8);
  if (fq == 0){
    Y[(size_t)node*2]   = o0 * dv;
    Y[(size_t)node*2+1] = o1 * dv;
  }
}

// ---------------- CSR gather final conv (D_out=2) ----------------
__global__ void k_gather2(const int* __restrict__ rowptr, const int* __restrict__ col,
                          const float* __restrict__ h2, const float* __restrict__ dinv,
                          const float* __restrict__ b, float* __restrict__ out){
  int d = blockIdx.x*256 + threadIdx.x;
  if (d >= NN) return;
  int beg = rowptr[d], end = rowptr[d+1];
  float a0 = h2[(size_t)d*2];
  float a1 = h2[(size_t)d*2+1];
  for (int j = beg; j < end; ++j){
    int s = col[j];
    a0 += h2[(size_t)s*2];
    a1 += h2[(size_t)s*2+1];
  }
  float dv = dinv[d];
  out[(size_t)d*2]   = fmaf(a0, dv, b[0]);
  out[(size_t)d*2+1] = fmaf(a1, dv, b[1]);
}

// ---------------- standalone dropout (fallback path only) ----------------
__global__ void k_dropout(const float* __restrict__ last, float* __restrict__ xemb){
  unsigned i = blockIdx.x*256 + threadIdx.x;
  if (i >= NF) return;
  xemb[i] = dropout_val(last[i], i);
}

// ======== fallback (atomic scatter) kernels ========
__global__ void k_convinit(const float* __restrict__ h, const float* __restrict__ dinv,
                           const float* __restrict__ b, float* __restrict__ out){
  int i = blockIdx.x*256 + threadIdx.x;
  if (i >= NF) return;
  int v = i >> 6, c = i & 63;
  float dv = dinv[v];
  out[i] = h[i]*dv*dv + b[c];
}
__global__ void k_scatter64(const int* __restrict__ src, const int* __restrict__ dst, int ne,
                            const float* __restrict__ h, const float* __restrict__ dinv,
                            float* __restrict__ out){
  int lane = threadIdx.x & 63;
  int wid  = (blockIdx.x*256 + threadIdx.x) >> 6;
  int nw   = (gridDim.x*256) >> 6;
  for (int e = wid; e < ne; e += nw){
    int s = src[e], d = dst[e];
    float coef = dinv[s]*dinv[d];
    atomicAdd(&out[d*64 + lane], h[s*64 + lane]*coef);
  }
}
__global__ void k_layeragg(const int* __restrict__ recv, const int* __restrict__ srcn, int ne,
                           const float* __restrict__ last, float* __restrict__ acc){
  int lane = threadIdx.x & 63;
  int wid  = (blockIdx.x*256 + threadIdx.x) >> 6;
  int nw   = (gridDim.x*256) >> 6;
  for (int e = wid; e < ne; e += nw){
    int r = recv[e], s = srcn[e];
    atomicAdd(&acc[r*64 + lane], last[s*64 + lane]);
  }
}
__global__ void k_scale(const float* __restrict__ in, const float* __restrict__ ds, int dsidx,
                        float* __restrict__ out){
  int i = blockIdx.x*256 + threadIdx.x;
  if (i < NF) out[i] = in[i] / ds[dsidx];
}
__global__ void k_convinit2(const float* __restrict__ h2, const float* __restrict__ dinv,
                            const float* __restrict__ b, float* __restrict__ out){
  int i = blockIdx.x*256 + threadIdx.x;
  if (i >= NN*2) return;
  int v = i >> 1, c = i & 1;
  float dv = dinv[v];
  out[i] = h2[i]*dv*dv + b[c];
}
__global__ void k_scatter2(const int* __restrict__ src, const int* __restrict__ dst, int ne,
                           const float* __restrict__ h2, const float* __restrict__ dinv,
                           float* __restrict__ out){
  int e = blockIdx.x*256 + threadIdx.x;
  if (e >= ne) return;
  int s = src[e], d = dst[e];
  float coef = dinv[s]*dinv[d];
  atomicAdd(&out[d*2 + 0], h2[s*2 + 0]*coef);
  atomicAdd(&out[d*2 + 1], h2[s*2 + 1]*coef);
}

extern "C" void kernel_launch(void* const* d_in, const int* in_sizes, int n_in,
                              void* d_out, int out_size, void* d_ws, size_t ws_size,
                              hipStream_t stream) {
  const float* x    = (const float*)d_in[0];
  const int*   ei   = (const int*)  d_in[1];
  const int*   lei  = (const int*)  d_in[2];
  const float* degs = (const float*)d_in[3];
  const float* lW1  = (const float*)d_in[4];
  const float* lb1  = (const float*)d_in[5];
  const float* lW2  = (const float*)d_in[6];
  const float* lb2  = (const float*)d_in[7];
  const float* pW1  = (const float*)d_in[8];
  const float* pb1  = (const float*)d_in[9];
  const float* pW2  = (const float*)d_in[10];
  const float* pb2  = (const float*)d_in[11];
  float* out = (float*)d_out;

  const int gN  = (NN + 255)/256;
  const int gE  = (EE + 255)/256;
  const int gEL = (ELL + 255)/256;
  const int gNF = (NF + 255)/256;
  const int gG16 = (NN*16 + 255)/256;   // 6250

  const bool dual   = ws_size >= (size_t)WS_DUAL * 4;
  const bool single = ws_size >= (size_t)WS_SINGLE * 4;

  if (dual) {
    float* base   = (float*)d_ws;
    float* dinv   = base;
    int*   cnt    = (int*)(base + OFF_CNT);
    int*   bsum   = (int*)(base + OFF_BSUM);
    int*   flag   = bsum + 120;
    int*   rpA    = (int*)(base + OFF_RPA);
    int*   colA   = (int*)(base + OFF_COLA);
    int*   rpB    = (int*)(base + OFF_RPB);
    int*   colB   = (int*)(base + OFF_COLB);
    float* F0     = base + OFF_COLB + 1000000;
    float* F1     = F0 + NF;
    float* F2     = F1 + NF;
    uint2* H0     = (uint2*)(F2 + NF);
    uint2* H1     = H0 + (size_t)NN*16;
    uint2* H2     = H1 + (size_t)NN*16;
    uint2* H3     = H2 + (size_t)NN*16;

    auto build_csr = [&](const int* srcp, const int* dstp, int ne, int gEdges, int computeDinv,
                         int* rowptr, int* col, int* rank){
      k_degrank<<<gEdges, 256, 0, stream>>>(dstp, ne, cnt, rank);
      k_scanfused<<<NB_SCAN, 1024, 0, stream>>>(cnt, bsum, flag, rowptr, dinv, computeDinv, NN);
      k_fillrz<<<gEdges, 256, 0, stream>>>(srcp, dstp, ne, rowptr, rank, col, cnt, flag);
    };

    const int* s0 = ei;                  const int* d0 = s0 + EE;
    const int* s1 = ei + 2*(size_t)EE;   const int* d1 = s1 + EE;
    const int* s2 = ei + 4*(size_t)EE;   const int* d2 = s2 + EE;
    const int* r0 = lei;                 const int* ls0 = r0 + ELL;
    const int* r1 = lei + 2*(size_t)ELL; const int* ls1 = r1 + ELL;

    k_zerof<<<gN, 256, 0, stream>>>(cnt, NN, flag);

    // ---- surface 0 ----
    build_csr(s0, d0, EE, gE, 1, rpA, colA, (int*)F0);
    k_gemm64h<false><<<6250, 256, 0, stream>>>(x, lW1, dinv, NN, H0);
    k_gathergemmh<<<6250, 256, 0, stream>>>(rpA, colA, H0, dinv, lb1, lW2, H1);
    k_gather64hh<<<gG16, 256, 0, stream>>>(rpA, colA, H1, dinv, lb2, H2);            // last16 = H2
    // ---- surface 1 ----
    build_csr(s1, d1, EE, gE, 1, rpA, colA, (int*)F0);
    build_csr(ls0, r0, ELL, gEL, 0, rpB, colB, (int*)F0);
    k_gemm64h<false><<<6250, 256, 0, stream>>>(x + (size_t)NF, lW1 + 4096, dinv, NN, H0);
    k_gathergemmh<<<6250, 256, 0, stream>>>(rpA, colA, H0, dinv, lb1 + 64, lW2 + 4096, H1);
    k_gatherlfagg2h<false,true><<<gG16, 256, 0, stream>>>(rpA, colA, H1, dinv, lb2 + 64,
                                                          rpB, colB, H2, degs, 0, (void*)H3);  // last16 = H3
    // ---- surface 2 ----
    build_csr(s2, d2, EE, gE, 1, rpA, colA, (int*)F0);
    build_csr(ls1, r1, ELL, gEL, 0, rpB, colB, (int*)F0);
    k_gemm64h<false><<<6250, 256, 0, stream>>>(x + 2*(size_t)NF, lW1 + 8192, dinv, NN, H0);
    k_gathergemmh<<<6250, 256, 0, stream>>>(rpA, colA, H0, dinv, lb1 + 128, lW2 + 8192, H1);
    k_gatherlfagg2h<true,false><<<gG16, 256, 0, stream>>>(rpA, colA, H1, dinv, lb2 + 128,
                                                          rpB, colB, H3, degs, 1, (void*)F1); // F1 = x_emb f32
    // ---- predictor (CSR-A = surface-2 edges; dinv = surface-2 degrees) ----
    k_gemm64h<false><<<6250, 256, 0, stream>>>(F1, pW1, dinv, NN, H0);
    k_predgather2h<<<gG16, 256, 0, stream>>>(rpA, colA, H0, dinv, pb1, pW2, F2);     // F2 = h2' [N,2]
    k_gather2<<<gN, 256, 0, stream>>>(rpA, colA, F2, dinv, pb2, out);
    k_probe<<<1, 64, 0, stream>>>(ei, 0u, out);
    return;
  }

  if (single) {
    float* base   = (float*)d_ws;
    float* dinv   = base;
    int*   cnt    = (int*)(base + OFF_CNT);
    int*   bsum   = (int*)(base + OFF_BSUM);
    int*   flag   = bsum + 120;
    int*   rpA    = (int*)(base + OFF_RPA);
    int*   colA   = (int*)(base + OFF_COLA);
    float* F0     = base + OFF_RPB;
    float* F1     = F0 + NF;
    float* F2     = F1 + NF;

    auto build_csr = [&](const int* srcp, const int* dstp, int ne, int gEdges, int computeDinv,
                         int* rowptr, int* col, int* rank){
      k_zerof<<<gN, 256, 0, stream>>>(cnt, NN, flag);
      k_degrank<<<gEdges, 256, 0, stream>>>(dstp, ne, cnt, rank);
      k_scanfused<<<NB_SCAN, 1024, 0, stream>>>(cnt, bsum, flag, rowptr, dinv, computeDinv, NN);
      k_fillr<<<gEdges, 256, 0, stream>>>(srcp, dstp, ne, rowptr, rank, col);
    };

    const int* s0 = ei;                  const int* d0 = s0 + EE;
    const int* s1 = ei + 2*(size_t)EE;   const int* d1 = s1 + EE;
    const int* s2 = ei + 4*(size_t)EE;   const int* d2 = s2 + EE;
    const int* r0 = lei;                 const int* ls0 = r0 + ELL;
    const int* r1 = lei + 2*(size_t)ELL; const int* ls1 = r1 + ELL;

    build_csr(s0, d0, EE, gE, 1, rpA, colA, (int*)F0);
    k_gemm64<false,true><<<6250, 256, 0, stream>>>(x, lW1, dinv, NN, F0);
    k_gathergemm<<<6250, 256, 0, stream>>>(rpA, colA, F0, dinv, lb1, lW2, F1);
    k_gather64<<<gG16, 256, 0, stream>>>(rpA, colA, F1, dinv, lb2, F2);
    build_csr(s1, d1, EE, gE, 1, rpA, colA, (int*)F0);
    k_gemm64<false,true><<<6250, 256, 0, stream>>>(x + (size_t)NF, lW1 + 4096, dinv, NN, F0);
    k_gathergemm<<<6250, 256, 0, stream>>>(rpA, colA, F0, dinv, lb1 + 64, lW2 + 4096, F1);
    build_csr(ls0, r0, ELL, gEL, 0, rpA, colA, (int*)F0);
    k_agggather<false><<<gG16, 256, 0, stream>>>(rpA, colA, F1, F2, degs, 0, F0);
    build_csr(s2, d2, EE, gE, 1, rpA, colA, (int*)F1);
    k_gemm64<false,true><<<6250, 256, 0, stream>>>(x + 2*(size_t)NF, lW1 + 8192, dinv, NN, F1);
    k_gathergemm<<<6250, 256, 0, stream>>>(rpA, colA, F1, dinv, lb1 + 128, lW2 + 8192, F2);
    build_csr(ls1, r1, ELL, gEL, 0, rpA, colA, (int*)F1);
    k_agggather<true><<<gG16, 256, 0, stream>>>(rpA, colA, F2, F0, degs, 1, F1);
    build_csr(s2, d2, EE, gE, 0, rpA, colA, (int*)F0);
    k_gemm64<false,true><<<6250, 256, 0, stream>>>(F1, pW1, dinv, NN, F0);
    k_gather64<<<gG16, 256, 0, stream>>>(rpA, colA, F0, dinv, pb1, F2);
    k_gemm2<true,true><<<gN, 256, 0, stream>>>(F2, pW2, dinv, NN, F1);
    k_gather2<<<gN, 256, 0, stream>>>(rpA, colA, F1, dinv, pb2, out);
    k_probe<<<1, 64, 0, stream>>>(ei, 0u, out);
    return;
  }

  // ================= fallback: verified atomic-scatter path =================
  float* base = (float*)d_ws;
  float* dinv = base;
  int*   cnt  = (int*)(base + 100352);
  float* A    = base + 262144;
  float* B    = A + NF;
  float* C    = B + NF;

  for (int i = 0; i < 3; ++i){
    const int* srcp = ei + (size_t)i*2*EE;
    const int* dstp = srcp + EE;
    k_zero_int<<<gN, 256, 0, stream>>>(cnt, NN);
    k_deg<<<gE, 256, 0, stream>>>(dstp, EE, cnt);
    k_dinv<<<gN, 256, 0, stream>>>(cnt, dinv, NN);
    k_gemm64<false,false><<<6250, 256, 0, stream>>>(x + (size_t)i*NF, lW1 + (size_t)i*64*64, dinv, NN, A);
    k_convinit<<<gNF, 256, 0, stream>>>(A, dinv, lb1 + (size_t)i*64, B);
    k_scatter64<<<8192, 256, 0, stream>>>(srcp, dstp, EE, A, dinv, B);
    k_gemm64<true,false><<<6250, 256, 0, stream>>>(B, lW2 + (size_t)i*64*64, dinv, NN, A);
    float* T = (i == 0) ? C : B;
    k_convinit<<<gNF, 256, 0, stream>>>(A, dinv, lb2 + (size_t)i*64, T);
    k_scatter64<<<8192, 256, 0, stream>>>(srcp, dstp, EE, A, dinv, T);
    if (i > 0){
      const int* recvp = lei + (size_t)(i-1)*2*ELL;
      const int* lsrcp = recvp + ELL;
      k_layeragg<<<4096, 256, 0, stream>>>(recvp, lsrcp, ELL, C, B);
      k_scale<<<gNF, 256, 0, stream>>>(B, degs, i-1, C);
    }
  }
  k_dropout<<<gNF, 256, 0, stream>>>(C, B);
  const int* srcp = ei + (size_t)2*2*EE;
  const int* dstp = srcp + EE;
  k_gemm64<false,false><<<6250, 256, 0, stream>>>(B, pW1, dinv, NN, A);
  k_convinit<<<gNF, 256, 0, stream>>>(A, dinv, pb1, C);
  k_scatter64<<<8192, 256, 0, stream>>>(srcp, dstp, EE, A, dinv, C);
  k_gemm2<true,false><<<gN, 256, 0, stream>>>(C, pW2, dinv, NN, B);
  k_convinit2<<<(NN*2 + 255)/256, 256, 0, stream>>>(B, dinv, pb2, out);
  k_scatter2<<<gE, 256, 0, stream>>>(srcp, dstp, EE, B, dinv, out);
  k_probe<<<1, 64, 0, stream>>>(ei, 0u, out);
}